// Round 4
// baseline (86.977 us; speedup 1.0000x reference)
//
#include <hip/hip_runtime.h>

#define Bx 16
#define Cx 64
#define Lx 512
#define Dx 768
#define NPx 68   // int((512+16)/8 + 2)
#define PER 7
#define TOT4 (Bx * Cx * NPx * (Dx / 4))  // 13,369,344 float4 in out
#define ROW4 (NPx * (Dx / 4))            // 13056 float4 per (b,c) row

// ---------------- Kernel A: m[b,l] = mean_c(x) / sqrt(var_c(x, ddof=1)) ----
__global__ void mean_var_kernel(const float* __restrict__ x,
                                float* __restrict__ m) {
    int idx = blockIdx.x * blockDim.x + threadIdx.x;  // b*Lx + l
    if (idx >= Bx * Lx) return;
    int b = idx / Lx, l = idx - b * Lx;
    const float* xp = x + (size_t)b * Cx * Lx + l;
    float s = 0.f, ss = 0.f;
#pragma unroll 8
    for (int c = 0; c < Cx; ++c) {
        float v = xp[(size_t)c * Lx];
        s += v;
        ss += v * v;
    }
    float mean = s / (float)Cx;
    float var = (ss - s * s / (float)Cx) / (float)(Cx - 1);
    m[idx] = mean * rsqrtf(var);
}

// ---------------- Kernel B: per-(b,c) decompose + projections -> p[bc][768] -
__global__ __launch_bounds__(256) void token_kernel(
    const float* __restrict__ x, const float* __restrict__ gamma,
    const float* __restrict__ beta, const float* __restrict__ m,
    const float* __restrict__ w_t, const float* __restrict__ b_t,
    const float* __restrict__ w_s, const float* __restrict__ b_s,
    const float* __restrict__ w_r, const float* __restrict__ b_r,
    const float* __restrict__ w_g, const float* __restrict__ b_g,
    float* __restrict__ p) {
    __shared__ __align__(16) float s_xt[Lx];
    __shared__ __align__(16) float s_tr[Lx];
    __shared__ __align__(16) float s_det[Lx];
    __shared__ __align__(16) float s_se[Lx];
    __shared__ __align__(16) float s_res[Lx];
    __shared__ float s_ph[PER];
    __shared__ __align__(16) float s_cat[48];

    const int bc = blockIdx.x;  // b*Cx + c
    const int b = bc >> 6;
    const int tid = threadIdx.x;

    const float* xp = x + (size_t)bc * Lx;
    const float* gp = gamma + (size_t)bc * Lx;
    const float* bp = beta + (size_t)bc * Lx;
    const float* mp = m + (size_t)b * Lx;

    // 1. xt = gamma*(x - m) + beta
#pragma unroll
    for (int u = 0; u < 2; ++u) {
        int l = tid + u * 256;
        s_xt[l] = gp[l] * (xp[l] - mp[l]) + bp[l];
    }
    __syncthreads();

    // 2. trend (7-pt centered MA) + det on interior
#pragma unroll
    for (int u = 0; u < 2; ++u) {
        int l = tid + u * 256;
        float t = 0.f, d = 0.f;
        if (l >= 3 && l <= Lx - 4) {
#pragma unroll
            for (int k = -3; k <= 3; ++k) t += s_xt[l + k];
            t *= (1.f / 7.f);
            d = s_xt[l] - t;
        }
        s_tr[l] = t;
        s_det[l] = d;
    }
    __syncthreads();

    // 3. per-phase averages: 7 phases x 32 lanes, shuffle-reduce
    if (tid < 224) {
        int ph = tid >> 5, j = tid & 31;
        int l0 = ph + 7 * ((3 - ph + 6) / 7);  // first valid l of phase ph
        int cnt = (Lx - 4 - l0) / 7 + 1;
        float sum = 0.f;
#pragma unroll
        for (int k = 0; k < 3; ++k) {
            int idx = j + 32 * k;
            if (idx < cnt) sum += s_det[l0 + 7 * idx];  // stride-7: bank-free
        }
#pragma unroll
        for (int off = 16; off >= 1; off >>= 1) sum += __shfl_xor(sum, off);
        if (j == 0) s_ph[ph] = sum / (float)cnt;
    }
    __syncthreads();
    if (tid == 0) {
        float mn = 0.f;
#pragma unroll
        for (int q = 0; q < PER; ++q) mn += s_ph[q];
        mn *= (1.f / 7.f);
#pragma unroll
        for (int q = 0; q < PER; ++q) s_ph[q] -= mn;
    }
    __syncthreads();

    // 4. seasonal (all l) + resid (interior)
#pragma unroll
    for (int u = 0; u < 2; ++u) {
        int l = tid + u * 256;
        float se = s_ph[l % PER];
        s_se[l] = se;
        s_res[l] = (l >= 3 && l <= Lx - 4) ? (s_det[l] - se) : 0.f;
    }
    __syncthreads();

    // 5. cat[48]: three Linear(512->16); 4 lanes per output
    if (tid < 192) {
        int j = tid >> 2, q = tid & 3;
        const float* stream;
        const float* w;
        const float* bias;
        int jj;
        if (j < 16) {
            stream = s_tr; w = w_t; bias = b_t; jj = j;
        } else if (j < 32) {
            stream = s_se; w = w_s; bias = b_s; jj = j - 16;
        } else {
            stream = s_res; w = w_r; bias = b_r; jj = j - 32;
        }
        const float4* wr =
            reinterpret_cast<const float4*>(w + (size_t)jj * Lx + q * 128);
        const float4* sp = reinterpret_cast<const float4*>(stream + q * 128);
        float acc = 0.f;
#pragma unroll 8
        for (int i = 0; i < 32; ++i) {
            float4 a = sp[i], wv = wr[i];
            acc += a.x * wv.x + a.y * wv.y + a.z * wv.z + a.w * wv.w;
        }
        acc += __shfl_xor(acc, 1);
        acc += __shfl_xor(acc, 2);
        if (q == 0) s_cat[j] = acc + bias[jj];
    }
    __syncthreads();

    // 6. p[bc][768] = cat @ w_g.T + b_g
    {
        const float4* c4 = reinterpret_cast<const float4*>(s_cat);
        float* prow = p + (size_t)bc * Dx;
#pragma unroll
        for (int u = 0; u < 3; ++u) {
            int d = tid + u * 256;
            const float4* wg4 =
                reinterpret_cast<const float4*>(w_g + (size_t)d * 48);
            float acc = 0.f;
#pragma unroll
            for (int kk = 0; kk < 12; ++kk) {
                float4 w4 = wg4[kk], cc = c4[kk];
                acc += w4.x * cc.x + w4.y * cc.y + w4.z * cc.z + w4.w * cc.w;
            }
            prow[d] = acc + b_g[d];
        }
    }
}

// ---------------- Kernel C: fill-shaped expand -----------------------------
// Globally LINEAR float4 store stream (same shape as fillBufferAligned):
// out4[i4] = p4[bc*192 + d4], bc = i4/13056, d4 = (i4 - bc*13056) % 192.
// p is 3 MB -> L2/LLC resident; the only HBM traffic is the sequential write.
__global__ __launch_bounds__(256) void expand_kernel(
    const float4* __restrict__ p4, float4* __restrict__ out4) {
    int stride = gridDim.x * 256;
    for (int i4 = blockIdx.x * 256 + threadIdx.x; i4 < TOT4; i4 += stride) {
        int bc = (int)((unsigned)i4 / (unsigned)ROW4);         // magic mul
        int r = i4 - bc * ROW4;
        int d4 = (int)((unsigned)r % 192u);                    // magic mul
        out4[i4] = p4[bc * 192 + d4];
    }
}

extern "C" void kernel_launch(void* const* d_in, const int* in_sizes, int n_in,
                              void* d_out, int out_size, void* d_ws,
                              size_t ws_size, hipStream_t stream) {
    const float* data_x = (const float*)d_in[0];
    // d_in[1] = data_y (unused by the reference)
    const float* gamma = (const float*)d_in[2];
    const float* beta = (const float*)d_in[3];
    const float* w_t = (const float*)d_in[4];
    const float* b_t = (const float*)d_in[5];
    const float* w_s = (const float*)d_in[6];
    const float* b_s = (const float*)d_in[7];
    const float* w_r = (const float*)d_in[8];
    const float* b_r = (const float*)d_in[9];
    const float* w_g = (const float*)d_in[10];
    const float* b_g = (const float*)d_in[11];
    float* out = (float*)d_out;

    float* m = (float*)d_ws;                    // 16*512 floats = 32 KB
    float* p = (float*)d_ws + Bx * Lx;          // 1024*768 floats = 3 MB

    mean_var_kernel<<<(Bx * Lx + 255) / 256, 256, 0, stream>>>(data_x, m);

    token_kernel<<<Bx * Cx, 256, 0, stream>>>(data_x, gamma, beta, m, w_t, b_t,
                                              w_s, b_s, w_r, b_r, w_g, b_g, p);

    expand_kernel<<<4096, 256, 0, stream>>>(
        reinterpret_cast<const float4*>(p), reinterpret_cast<float4*>(out));
}